// Round 11
// baseline (52.126 us; speedup 1.0000x reference)
//
#include <hip/hip_runtime.h>

#define LENY  1048576
#define NU    (LENY - 1)      // length of u_combined
#define NRBF  11
#define NB    2048            // 8 blocks/CU, <=64 VGPR -> all co-resident
#define NT    256             // 4 waves per block
#define NW    (NT / 64)
#define PERT  2               // consecutive elements per thread
#define CHUNK (NT * PERT)     // 512; NB*CHUNK == LENY
#define SEGB  32              // blocks per segment
#define NSEG  (NB / SEGB)     // 64 segments

typedef float v4f __attribute__((ext_vector_type(4)));

#define L2E 1.44269504088896340736f   // log2(e)

__device__ __forceinline__ float fexp(float x) {
    return __builtin_amdgcn_exp2f(x * L2E);
}
__device__ __forceinline__ float sigmoid10(float x) {
    x = fminf(10.0f, fmaxf(-10.0f, x));
    const float e = __builtin_amdgcn_exp2f(-x * L2E);
    return __builtin_amdgcn_rcpf(1.0f + e);
}

// Relaxed agent-scope atomics: reach the coherence point, emit NO
// buffer_inv/buffer_wbl2 cache maintenance (acq/rel poisoned R2: 62us).
__device__ __forceinline__ void st_relaxed_u64(unsigned long long* p, unsigned long long v) {
    __hip_atomic_store(p, v, __ATOMIC_RELAXED, __HIP_MEMORY_SCOPE_AGENT);
}
__device__ __forceinline__ unsigned long long ld_relaxed_u64(const unsigned long long* p) {
    return __hip_atomic_load(p, __ATOMIC_RELAXED, __HIP_MEMORY_SCOPE_AGENT);
}
__device__ __forceinline__ void st_relaxed_u32(unsigned* p, unsigned v) {
    __hip_atomic_store(p, v, __ATOMIC_RELAXED, __HIP_MEMORY_SCOPE_AGENT);
}
__device__ __forceinline__ unsigned ld_relaxed_u32(const unsigned* p) {
    return __hip_atomic_load(p, __ATOMIC_RELAXED, __HIP_MEMORY_SCOPE_AGENT);
}
__device__ __forceinline__ unsigned fadd_relaxed_u32(unsigned* p, unsigned v) {
    return __hip_atomic_fetch_add(p, v, __ATOMIC_RELAXED, __HIP_MEMORY_SCOPE_AGENT);
}
__device__ __forceinline__ double bitsd(unsigned long long v) {
    return __builtin_bit_cast(double, v);
}
__device__ __forceinline__ unsigned long long dbits(double v) {
    return __builtin_bit_cast(unsigned long long, v);
}

// Fused scan with two-level segmented sync:
//  - every block publishes agg[b] (+flag, after vmcnt drain)
//  - per-segment arrival counter elects the 32nd arriver, which sums the
//    segment's 32 aggs (all at L3: each drained before its counter add)
//    and publishes segtot[s] (+segf)
//  - lookback per block: <=31 in-segment flags (wave 0, parallel lanes) +
//    <=63 segment flags (wave 1, parallel lanes). No serial chain, no
//    global barrier, all deps point to LOWER block indices.
__global__ __launch_bounds__(NT, 8) void rbf_seg(
    const float2* __restrict__ yin,
    const float2* __restrict__ xa,
    const float2* __restrict__ xb,
    const float*  __restrict__ rbfw_raw,
    const float*  __restrict__ weights,
    const float*  __restrict__ g1raw,
    const float*  __restrict__ g2raw,
    float2* __restrict__ yout,
    float2* __restrict__ uout,
    double2* __restrict__ agg,
    double2* __restrict__ segtot,
    unsigned* __restrict__ flags,
    unsigned* __restrict__ segcnt,
    unsigned* __restrict__ segf)
{
    const int b = blockIdx.x, t = threadIdx.x;
    const int lane = t & 63, wid = t >> 6;
    const int base = b * CHUNK + t * PERT;
    const int seg = b >> 5, sb = seg << 5;

    // ---- uniform params ----
    const float RBFw    = sigmoid10(rbfw_raw[0]);
    const float wdt     = RBFw * 0.2f;
    const float negInvL = -L2E / (2.0f * wdt * wdt);
    const float g1 = fexp(g1raw[0]);
    const float g2 = fexp(g2raw[0]);
    const float Bf = (float)(1.0 / 60.0);
    const float2 y0 = yin[0];

    float wj[NRBF];
    #pragma unroll
    for (int j = 0; j < NRBF; ++j) wj[j] = weights[j];

    // ---- 16B/lane cached input loads (L3-resident across replays) ----
    const v4f yv = *((const v4f*)yin + (base >> 1));
    const v4f av = *((const v4f*)xa  + (base >> 1));
    const v4f bv = *((const v4f*)xb  + (base >> 1));

    // ---- compute u in registers, per-thread double sums ----
    float ux[PERT], uy[PERT];
    double sx = 0.0, sy = 0.0;
    #pragma unroll
    for (int k = 0; k < PERT; ++k) {
        const int gi = base + k;
        const float ti = ((float)gi - 524287.5f) / 524287.5f;
        float dot = 0.0f;
        #pragma unroll
        for (int j = 0; j < NRBF; ++j) {
            const float c = -1.0f + 0.2f * (float)j;
            const float d = ti - c;
            dot += __builtin_amdgcn_exp2f(d * d * negInvL) * wj[j];
        }
        const float wt = sigmoid10(dot);
        const float eyx = yv[2*k], eyy = yv[2*k+1];
        const float eax = av[2*k], eay = av[2*k+1];
        const float ebx = bv[2*k], eby = bv[2*k+1];
        const float u1x = -g1 * (eyx - eax);
        const float u1y = -g1 * (eyy - eay);
        const float u2x = -g2 * (eyx - ebx);
        const float u2y = -g2 * (eyy - eby);
        ux[k] = u1x * (1.0f - wt) + u2x * wt;
        uy[k] = u1y * (1.0f - wt) + u2y * wt;
        sx += (double)(ux[k] * Bf);   // phantom elem LENY-1: its contribution
        sy += (double)(uy[k] * Bf);   // never reaches any STORED prefix
    }

    // ---- block scan: wave shfl_up + wave totals (1 barrier) ----
    double ix = sx, iy = sy;
    #pragma unroll
    for (int d = 1; d < 64; d <<= 1) {
        const double px = __shfl_up(ix, d, 64);
        const double py = __shfl_up(iy, d, 64);
        if (lane >= d) { ix += px; iy += py; }
    }
    __shared__ double2 wtot[NW];
    if (lane == 63) wtot[wid] = make_double2(ix, iy);
    __syncthreads();
    double wbx = 0.0, wby = 0.0, totx = 0.0, toty = 0.0;
    #pragma unroll
    for (int w = 0; w < NW; ++w) {
        const double vx = wtot[w].x, vy = wtot[w].y;
        totx += vx; toty += vy;
        if (w < wid) { wbx += vx; wby += vy; }
    }
    const double myex = wbx + ix - sx;   // exclusive in-block prefix
    const double myey = wby + iy - sy;

    // ---- publish agg, arrive on segment counter, maybe sweep segment ----
    if (t == 0) {
        st_relaxed_u64((unsigned long long*)&agg[b].x, dbits(totx));
        st_relaxed_u64((unsigned long long*)&agg[b].y, dbits(toty));
        asm volatile("s_waitcnt vmcnt(0)" ::: "memory");   // agg at L3
        st_relaxed_u32(&flags[b], 1u);
        const unsigned old = fadd_relaxed_u32(&segcnt[seg], 1u);
        if (old == SEGB - 1u) {
            // 32nd arriver: all 32 aggs are at L3 (each drained pre-add)
            asm volatile("" ::: "memory");
            double tx = 0.0, ty = 0.0;
            #pragma unroll
            for (int i = 0; i < SEGB; ++i) {   // fixed order -> deterministic
                tx += bitsd(ld_relaxed_u64((const unsigned long long*)&agg[sb + i].x));
                ty += bitsd(ld_relaxed_u64((const unsigned long long*)&agg[sb + i].y));
            }
            st_relaxed_u64((unsigned long long*)&segtot[seg].x, dbits(tx));
            st_relaxed_u64((unsigned long long*)&segtot[seg].y, dbits(ty));
            asm volatile("s_waitcnt vmcnt(0)" ::: "memory");
            st_relaxed_u32(&segf[seg], 1u);
        }
    }

    // ---- store u while sync propagates (overlaps the waits) ----
    if (base + PERT <= NU) {
        v4f r = { ux[0], uy[0], ux[1], uy[1] };
        __builtin_nontemporal_store(r, (v4f*)uout + (base >> 1));
    } else {
        for (int k = 0; k < PERT; ++k)
            if (base + k < NU) uout[base + k] = make_float2(ux[k], uy[k]);
    }

    // ---- bounded parallel lookback ----
    double ox = 0.0, oy = 0.0;
    if (wid == 0) {
        const int nPred = b - sb;              // 0..31 in-segment predecessors
        if (lane < nPred) {
            const int i = sb + lane;
            while (ld_relaxed_u32(&flags[i]) == 0u) __builtin_amdgcn_s_sleep(1);
            asm volatile("" ::: "memory");
            ox = bitsd(ld_relaxed_u64((const unsigned long long*)&agg[i].x));
            oy = bitsd(ld_relaxed_u64((const unsigned long long*)&agg[i].y));
        }
    } else if (wid == 1) {
        if (lane < seg) {                      // 0..63 preceding segment totals
            while (ld_relaxed_u32(&segf[lane]) == 0u) __builtin_amdgcn_s_sleep(1);
            asm volatile("" ::: "memory");
            ox = bitsd(ld_relaxed_u64((const unsigned long long*)&segtot[lane].x));
            oy = bitsd(ld_relaxed_u64((const unsigned long long*)&segtot[lane].y));
        }
    }
    #pragma unroll
    for (int d = 32; d > 0; d >>= 1) {
        ox += __shfl_down(ox, d);
        oy += __shfl_down(oy, d);
    }
    __shared__ double2 wred[NW];
    if (lane == 0) wred[wid] = make_double2(ox, oy);
    __syncthreads();
    const double offx = wred[0].x + wred[1].x + wred[2].x + wred[3].x;
    const double offy = wred[0].y + wred[1].y + wred[2].y + wred[3].y;

    // ---- exclusive-scan y write (16B nt stores; y[0]=yin[0] falls out) ----
    double runx = offx + myex, runy = offy + myey;
    const double y0x = (double)y0.x, y0y = (double)y0.y;

    const float o0x = (float)(y0x + runx);
    const float o0y = (float)(y0y + runy);
    runx += (double)(ux[0] * Bf);
    runy += (double)(uy[0] * Bf);
    const float o1x = (float)(y0x + runx);
    const float o1y = (float)(y0y + runy);
    v4f r = { o0x, o0y, o1x, o1y };
    __builtin_nontemporal_store(r, (v4f*)yout + (base >> 1));
}

extern "C" void kernel_launch(void* const* d_in, const int* in_sizes, int n_in,
                              void* d_out, int out_size, void* d_ws, size_t ws_size,
                              hipStream_t stream) {
    const float2* yin  = (const float2*)d_in[0];
    const float2* xa   = (const float2*)d_in[1];
    const float2* xb   = (const float2*)d_in[2];
    const float*  rbfw = (const float*)d_in[3];
    const float*  wts  = (const float*)d_in[4];
    const float*  g1   = (const float*)d_in[5];
    const float*  g2   = (const float*)d_in[6];

    float*  out  = (float*)d_out;
    float2* yout = (float2*)out;                 // y: LENY x 2
    float2* uout = (float2*)(out + 2 * LENY);    // u_combined: (LENY-1) x 2

    char* ws = (char*)d_ws;
    double2*  agg    = (double2*)ws;                      // 32 KB @ 0
    double2*  stot   = (double2*)(ws + 32768);            //  1 KB @ 32768
    unsigned* flags  = (unsigned*)(ws + 33792);           //  8 KB @ 33792
    unsigned* segcnt = (unsigned*)(ws + 33792 + 8192);    // 256 B
    unsigned* segf   = (unsigned*)(ws + 33792 + 8448);    // 256 B

    // zero flags + segment counters + segment flags (contiguous 8.7 KB);
    // required every replay (d_ws is not re-poisoned between replays).
    hipMemsetAsync(flags, 0, 8192 + 512, stream);

    rbf_seg<<<NB, NT, 0, stream>>>(yin, xa, xb, rbfw, wts, g1, g2,
                                   yout, uout, agg, stot, flags, segcnt, segf);
}

// Round 12
// 22.921 us; speedup vs baseline: 2.2742x; 2.2742x over previous
//
#include <hip/hip_runtime.h>

#define LENY  1048576
#define NU    (LENY - 1)      // length of u_combined
#define NRBF  11

// ---- k1 geometry: deep per-thread batches (fill-kernel-style streaming) ----
#define NB1   512
#define NT1   256
#define PERT1 8
#define CHUNK1 (NT1 * PERT1)  // 2048; NB1*CHUNK1 == LENY

// ---- k2 geometry: R6-proven ----
#define NB2   2048
#define NT2   256
#define PERT2 2
#define CHUNK2 (NT2 * PERT2)  // 512; NB2*CHUNK2 == LENY

#define NW    4               // waves per 256-thread block

typedef float v4f __attribute__((ext_vector_type(4)));

#define L2E 1.44269504088896340736f   // log2(e)

__device__ __forceinline__ float fexp(float x) {
    return __builtin_amdgcn_exp2f(x * L2E);
}
__device__ __forceinline__ float sigmoid10(float x) {
    x = fminf(10.0f, fmaxf(-10.0f, x));
    const float e = __builtin_amdgcn_exp2f(-x * L2E);
    return __builtin_amdgcn_rcpf(1.0f + e);
}

// ---- k1: compute u (write it) + per-block double sums; deep MLP batches ----
__global__ __launch_bounds__(NT1) void rbf_k1(
    const float2* __restrict__ yin,
    const float2* __restrict__ xa,
    const float2* __restrict__ xb,
    const float*  __restrict__ rbfw_raw,
    const float*  __restrict__ weights,
    const float*  __restrict__ g1raw,
    const float*  __restrict__ g2raw,
    float2* __restrict__ uout,
    double2* __restrict__ bsums)   // bsums[] indexed by k2-chunk (512 elems): 2048 entries
{
    const int b = blockIdx.x, t = threadIdx.x;
    const int lane = t & 63, wid = t >> 6;
    const int base = b * CHUNK1 + t * PERT1;

    const float RBFw    = sigmoid10(rbfw_raw[0]);
    const float wdt     = RBFw * 0.2f;
    const float negInvL = -L2E / (2.0f * wdt * wdt);
    const float g1 = fexp(g1raw[0]);
    const float g2 = fexp(g2raw[0]);
    const float Bf = (float)(1.0 / 60.0);

    float wj[NRBF];
    #pragma unroll
    for (int j = 0; j < NRBF; ++j) wj[j] = weights[j];

    // 12 independent 16B cached loads in flight per thread
    const v4f* yp = (const v4f*)yin + (base >> 1);
    const v4f* ap = (const v4f*)xa  + (base >> 1);
    const v4f* bp = (const v4f*)xb  + (base >> 1);
    v4f yv[4], av[4], bv[4];
    #pragma unroll
    for (int q = 0; q < 4; ++q) { yv[q] = yp[q]; av[q] = ap[q]; bv[q] = bp[q]; }

    float ux[PERT1], uy[PERT1];
    double sx = 0.0, sy = 0.0;
    #pragma unroll
    for (int k = 0; k < PERT1; ++k) {
        const int gi = base + k;
        const float ti = ((float)gi - 524287.5f) / 524287.5f;
        float dot = 0.0f;
        #pragma unroll
        for (int j = 0; j < NRBF; ++j) {
            const float c = -1.0f + 0.2f * (float)j;   // linspace(-1,1,11)
            const float d = ti - c;
            dot += __builtin_amdgcn_exp2f(d * d * negInvL) * wj[j];
        }
        const float wt = sigmoid10(dot);
        const float eyx = yv[k >> 1][(k & 1) * 2 + 0];
        const float eyy = yv[k >> 1][(k & 1) * 2 + 1];
        const float eax = av[k >> 1][(k & 1) * 2 + 0];
        const float eay = av[k >> 1][(k & 1) * 2 + 1];
        const float ebx = bv[k >> 1][(k & 1) * 2 + 0];
        const float eby = bv[k >> 1][(k & 1) * 2 + 1];
        const float u1x = -g1 * (eyx - eax);
        const float u1y = -g1 * (eyy - eay);
        const float u2x = -g2 * (eyx - ebx);
        const float u2y = -g2 * (eyy - eby);
        ux[k] = u1x * (1.0f - wt) + u2x * wt;
        uy[k] = u1y * (1.0f - wt) + u2y * wt;
    }

    // store u (cached: k2 re-reads it; element NU does not exist)
    if (base + PERT1 <= NU) {
        v4f* up = (v4f*)uout + (base >> 1);
        #pragma unroll
        for (int q = 0; q < 4; ++q) {
            v4f r = { ux[2*q], uy[2*q], ux[2*q+1], uy[2*q+1] };
            up[q] = r;
        }
    } else {
        for (int k = 0; k < PERT1; ++k)
            if (base + k < NU) uout[base + k] = make_float2(ux[k], uy[k]);
    }

    // per-thread double sums, SPLIT per k2-chunk (4 k2-chunks per k1 block;
    // each 128-thread half-wave pair covers one 512-elem k2 chunk exactly:
    // threads 0..63 + 64..127 -> chunk 0, etc. PERT1*128 = 1024? No:
    // 512 elems / 8 per thread = 64 threads per k2 chunk -> one WAVE holds
    // exactly one k2 chunk (64 thr * 8 = 512). Chunk id = b*4 + wid... with
    // NW=4 waves and 4 chunks per block, chunk = b*4 + wid.
    #pragma unroll
    for (int k = 0; k < PERT1; ++k) {
        sx += (double)(ux[k] * Bf);   // phantom elem LENY-1 harmless: its block
        sy += (double)(uy[k] * Bf);   // sum is consumed by no later chunk
    }
    // wave reduce = k2-chunk total (64 thr * 8 elem = 512 = CHUNK2)
    #pragma unroll
    for (int d = 32; d > 0; d >>= 1) {
        sx += __shfl_down(sx, d);
        sy += __shfl_down(sy, d);
    }
    if (lane == 0) bsums[b * NW + wid] = make_double2(sx, sy);
}

// ---- k2: block offset from bsums + in-block scan + y write (R6-proven) ----
__global__ __launch_bounds__(NT2) void rbf_k2(
    const float2* __restrict__ yin,
    const float2* __restrict__ uin,
    const double2* __restrict__ bsums,
    float2* __restrict__ yout)
{
    const int b = blockIdx.x, t = threadIdx.x;
    const int lane = t & 63, wid = t >> 6;
    const int base = b * CHUNK2 + t * PERT2;
    const float Bf = (float)(1.0 / 60.0);

    // ---- load this thread's u pair (guard only the single OOB tail lane) ----
    float u0x, u0y, u1x, u1y;
    if (base + PERT2 <= NU) {
        const v4f uv = *((const v4f*)uin + (base >> 1));
        u0x = uv[0]; u0y = uv[1]; u1x = uv[2]; u1y = uv[3];
    } else {
        const float2 z0 = (base < NU) ? uin[base] : make_float2(0.f, 0.f);
        u0x = z0.x; u0y = z0.y; u1x = 0.0f; u1y = 0.0f;
    }

    // ---- block offset: sum bsums[0..b-1], <=8 cached strided loads ----
    double ox = 0.0, oy = 0.0;
    for (int j = t; j < b; j += NT2) { ox += bsums[j].x; oy += bsums[j].y; }
    #pragma unroll
    for (int d = 32; d > 0; d >>= 1) {
        ox += __shfl_down(ox, d);
        oy += __shfl_down(oy, d);
    }

    // ---- per-thread sum + wave inclusive scan ----
    const double s0x = (double)(u0x * Bf), s0y = (double)(u0y * Bf);
    const double s1x = (double)(u1x * Bf), s1y = (double)(u1y * Bf);
    const double  sx = s0x + s1x, sy = s0y + s1y;
    double ix = sx, iy = sy;
    #pragma unroll
    for (int d = 1; d < 64; d <<= 1) {
        const double px = __shfl_up(ix, d, 64);
        const double py = __shfl_up(iy, d, 64);
        if (lane >= d) { ix += px; iy += py; }
    }

    // single barrier: offset partials + scan wave totals in separate arrays
    __shared__ double2 wred[NW];
    __shared__ double2 wtot[NW];
    if (lane == 0)  wred[wid] = make_double2(ox, oy);
    if (lane == 63) wtot[wid] = make_double2(ix, iy);
    __syncthreads();

    double offx = 0.0, offy = 0.0, wbx = 0.0, wby = 0.0;
    #pragma unroll
    for (int w = 0; w < NW; ++w) {
        offx += wred[w].x; offy += wred[w].y;
        if (w < wid) { wbx += wtot[w].x; wby += wtot[w].y; }
    }
    const double myex = wbx + ix - sx;   // exclusive prefix within block
    const double myey = wby + iy - sy;

    // ---- y write: y[i] = y0 + (offset + exclusive prefix at i) ----
    const float2 y0 = yin[0];
    double runx = offx + myex, runy = offy + myey;
    const double y0x = (double)y0.x, y0y = (double)y0.y;

    const float o0x = (float)(y0x + runx);
    const float o0y = (float)(y0y + runy);
    runx += s0x; runy += s0y;
    const float o1x = (float)(y0x + runx);
    const float o1y = (float)(y0y + runy);
    v4f r = { o0x, o0y, o1x, o1y };
    __builtin_nontemporal_store(r, (v4f*)yout + (base >> 1));
}

extern "C" void kernel_launch(void* const* d_in, const int* in_sizes, int n_in,
                              void* d_out, int out_size, void* d_ws, size_t ws_size,
                              hipStream_t stream) {
    const float2* yin  = (const float2*)d_in[0];
    const float2* xa   = (const float2*)d_in[1];
    const float2* xb   = (const float2*)d_in[2];
    const float*  rbfw = (const float*)d_in[3];
    const float*  wts  = (const float*)d_in[4];
    const float*  g1   = (const float*)d_in[5];
    const float*  g2   = (const float*)d_in[6];

    float*  out  = (float*)d_out;
    float2* yout = (float2*)out;                 // y: LENY x 2
    float2* uout = (float2*)(out + 2 * LENY);    // u_combined: (LENY-1) x 2
    double2* bsums = (double2*)d_ws;             // 2048 * 16 B = 32 KB (k2-chunk sums)

    rbf_k1<<<NB1, NT1, 0, stream>>>(yin, xa, xb, rbfw, wts, g1, g2, uout, bsums);
    rbf_k2<<<NB2, NT2, 0, stream>>>(yin, uout, bsums, yout);
}

// Round 13
// 19.097 us; speedup vs baseline: 2.7295x; 1.2002x over previous
//
#include <hip/hip_runtime.h>

#define LENY  1048576
#define NU    (LENY - 1)      // length of u_combined
#define NRBF  11
#define NB    2048            // blocks: 8/CU -> 32 waves/CU = full occupancy
#define NT    256             // threads per block (4 waves)
#define NW    (NT / 64)
#define PERT  2               // consecutive elements per thread
#define CHUNK (NT * PERT)     // 512; NB*CHUNK == LENY

typedef float v4f __attribute__((ext_vector_type(4)));

#define L2E 1.44269504088896340736f   // log2(e)

__device__ __forceinline__ float fexp(float x) {
    return __builtin_amdgcn_exp2f(x * L2E);
}
__device__ __forceinline__ float sigmoid10(float x) {
    x = fminf(10.0f, fmaxf(-10.0f, x));
    const float e = __builtin_amdgcn_exp2f(-x * L2E);
    return __builtin_amdgcn_rcpf(1.0f + e);
}

// ---------------- k1: compute u, write it, emit per-block double sums ------
__global__ __launch_bounds__(NT) void rbf_k1(
    const float2* __restrict__ yin,
    const float2* __restrict__ xa,
    const float2* __restrict__ xb,
    const float*  __restrict__ rbfw_raw,
    const float*  __restrict__ weights,
    const float*  __restrict__ g1raw,
    const float*  __restrict__ g2raw,
    float2* __restrict__ uout,
    double2* __restrict__ bsums)
{
    const int b = blockIdx.x, t = threadIdx.x;
    const int lane = t & 63, wid = t >> 6;
    const int base = b * CHUNK + t * PERT;

    const float RBFw    = sigmoid10(rbfw_raw[0]);
    const float wdt     = RBFw * 0.2f;
    const float negInvL = -L2E / (2.0f * wdt * wdt);
    const float g1 = fexp(g1raw[0]);
    const float g2 = fexp(g2raw[0]);
    const float Bf = (float)(1.0 / 60.0);

    float wj[NRBF];
    #pragma unroll
    for (int j = 0; j < NRBF; ++j) wj[j] = weights[j];

    // one float4 per stream = 16B/lane, nontemporal (streamed once)
    const v4f yv = __builtin_nontemporal_load((const v4f*)yin + (base >> 1));
    const v4f av = __builtin_nontemporal_load((const v4f*)xa  + (base >> 1));
    const v4f bv = __builtin_nontemporal_load((const v4f*)xb  + (base >> 1));

    float ux[PERT], uy[PERT];
    double sx = 0.0, sy = 0.0;
    #pragma unroll
    for (int k = 0; k < PERT; ++k) {
        const int gi = base + k;
        const float ti = ((float)gi - 524287.5f) / 524287.5f;
        float dot = 0.0f;
        #pragma unroll
        for (int j = 0; j < NRBF; ++j) {
            const float c = -1.0f + 0.2f * (float)j;
            const float d = ti - c;
            dot += __builtin_amdgcn_exp2f(d * d * negInvL) * wj[j];
        }
        const float wt = sigmoid10(dot);
        const float eyx = yv[2*k], eyy = yv[2*k+1];
        const float eax = av[2*k], eay = av[2*k+1];
        const float ebx = bv[2*k], eby = bv[2*k+1];
        const float u1x = -g1 * (eyx - eax);
        const float u1y = -g1 * (eyy - eay);
        const float u2x = -g2 * (eyx - ebx);
        const float u2y = -g2 * (eyy - eby);
        ux[k] = u1x * (1.0f - wt) + u2x * wt;
        uy[k] = u1y * (1.0f - wt) + u2y * wt;
        sx += (double)(ux[k] * Bf);   // phantom last elem included: its block
        sy += (double)(uy[k] * Bf);   // total is never consumed by stored prefix
    }

    // store u CACHED (k2 block b re-reads this exact range -> L2 hit)
    if (base + PERT <= NU) {
        v4f r = { ux[0], uy[0], ux[1], uy[1] };
        *((v4f*)uout + (base >> 1)) = r;
    } else {
        for (int k = 0; k < PERT; ++k)
            if (base + k < NU) uout[base + k] = make_float2(ux[k], uy[k]);
    }

    // block total: wave shfl_down reduce, then 4 wave totals
    #pragma unroll
    for (int d = 32; d > 0; d >>= 1) {
        sx += __shfl_down(sx, d);
        sy += __shfl_down(sy, d);
    }
    __shared__ double2 wtot[NW];
    if (lane == 0) wtot[wid] = make_double2(sx, sy);
    __syncthreads();
    if (t == 0) {
        double tx = 0.0, ty = 0.0;
        #pragma unroll
        for (int w = 0; w < NW; ++w) { tx += wtot[w].x; ty += wtot[w].y; }
        bsums[b] = make_double2(tx, ty);
    }
}

// ---------------- k2: block offset from bsums + in-block scan + y write ----
__global__ __launch_bounds__(NT) void rbf_k2(
    const float2* __restrict__ yin,
    const float2* __restrict__ uin,
    const double2* __restrict__ bsums,
    float2* __restrict__ yout)
{
    const int b = blockIdx.x, t = threadIdx.x;
    const int lane = t & 63, wid = t >> 6;
    const int base = b * CHUNK + t * PERT;
    const float Bf = (float)(1.0 / 60.0);

    // ---- load this thread's u pair (guard only the single OOB tail lane) ----
    float u0x, u0y, u1x, u1y;
    if (base + PERT <= NU) {
        const v4f uv = *((const v4f*)uin + (base >> 1));
        u0x = uv[0]; u0y = uv[1]; u1x = uv[2]; u1y = uv[3];
    } else {
        const float2 z0 = (base < NU) ? uin[base] : make_float2(0.f, 0.f);
        u0x = z0.x; u0y = z0.y; u1x = 0.0f; u1y = 0.0f;
    }

    // ---- block offset: sum bsums[0..b-1], <=8 cached loads per thread ----
    double ox = 0.0, oy = 0.0;
    for (int j = t; j < b; j += NT) { ox += bsums[j].x; oy += bsums[j].y; }
    #pragma unroll
    for (int d = 32; d > 0; d >>= 1) {
        ox += __shfl_down(ox, d);
        oy += __shfl_down(oy, d);
    }
    __shared__ double2 wred[NW];
    if (lane == 0) wred[wid] = make_double2(ox, oy);
    __syncthreads();
    double offx = 0.0, offy = 0.0;
    #pragma unroll
    for (int w = 0; w < NW; ++w) { offx += wred[w].x; offy += wred[w].y; }

    // ---- per-thread sum + wave inclusive scan + block exclusive prefix ----
    const double s0x = (double)(u0x * Bf), s0y = (double)(u0y * Bf);
    const double s1x = (double)(u1x * Bf), s1y = (double)(u1y * Bf);
    const double  sx = s0x + s1x, sy = s0y + s1y;
    double ix = sx, iy = sy;
    #pragma unroll
    for (int d = 1; d < 64; d <<= 1) {
        const double px = __shfl_up(ix, d, 64);
        const double py = __shfl_up(iy, d, 64);
        if (lane >= d) { ix += px; iy += py; }
    }
    __shared__ double2 wtot[NW];
    if (lane == 63) wtot[wid] = make_double2(ix, iy);
    __syncthreads();
    double wbx = 0.0, wby = 0.0;
    #pragma unroll
    for (int w = 0; w < NW; ++w)
        if (w < wid) { wbx += wtot[w].x; wby += wtot[w].y; }
    const double myex = wbx + ix - sx;   // exclusive prefix within block
    const double myey = wby + iy - sy;

    // ---- y write: y[i] = y0 + (offset + exclusive prefix at i) ----
    const float2 y0 = yin[0];
    double runx = offx + myex, runy = offy + myey;
    const double y0x = (double)y0.x, y0y = (double)y0.y;

    const float o0x = (float)(y0x + runx);
    const float o0y = (float)(y0y + runy);
    runx += s0x; runy += s0y;
    const float o1x = (float)(y0x + runx);
    const float o1y = (float)(y0y + runy);
    v4f r = { o0x, o0y, o1x, o1y };
    __builtin_nontemporal_store(r, (v4f*)yout + (base >> 1));
}

extern "C" void kernel_launch(void* const* d_in, const int* in_sizes, int n_in,
                              void* d_out, int out_size, void* d_ws, size_t ws_size,
                              hipStream_t stream) {
    const float2* yin  = (const float2*)d_in[0];
    const float2* xa   = (const float2*)d_in[1];
    const float2* xb   = (const float2*)d_in[2];
    const float*  rbfw = (const float*)d_in[3];
    const float*  wts  = (const float*)d_in[4];
    const float*  g1   = (const float*)d_in[5];
    const float*  g2   = (const float*)d_in[6];

    float*  out  = (float*)d_out;
    float2* yout = (float2*)out;                 // y: LENY x 2
    float2* uout = (float2*)(out + 2 * LENY);    // u_combined: (LENY-1) x 2
    double2* bsums = (double2*)d_ws;             // 2048 * 16 B = 32 KB

    rbf_k1<<<NB, NT, 0, stream>>>(yin, xa, xb, rbfw, wts, g1, g2, uout, bsums);
    rbf_k2<<<NB, NT, 0, stream>>>(yin, uout, bsums, yout);
}